// Round 1
// baseline (113.340 us; speedup 1.0000x reference)
//
#include <hip/hip_runtime.h>
#include <math.h>

#define DIM    4096
#define NB     1024
#define WPB    2                 // waves (= batch items) per block
#define NBLK   (NB / WPB)        // 512 blocks of 128 threads; LDS 64KB -> max 2 blocks/CU

typedef float v2f __attribute__((ext_vector_type(2)));

// parity of adjacent-bit products within 6 bits (pairs (0,1)..(4,5))
__host__ __device__ constexpr int czP5(int j) {
    return (((j >> 0) & (j >> 1)) ^ ((j >> 1) & (j >> 2)) ^ ((j >> 2) & (j >> 3)) ^
            ((j >> 3) & (j >> 4)) ^ ((j >> 4) & (j >> 5))) & 1;
}

// Fused (Ry*Rx) SU(2) gate on local bit G of a 64-amp register block, complex
// interleaved (lo=re, hi=im). Coefficients packed: P1=(cc,cs), P2=(ss,sc).
template<int G>
__device__ __forceinline__ void gate_pk(v2f (&x)[64], v2f P1, v2f P2) {
#pragma unroll
    for (int p = 0; p < 32; ++p) {
        const int j0 = ((p >> G) << (G + 1)) | (p & ((1 << G) - 1));
        const int j1 = j0 | (1 << G);
        const v2f x0 = x[j0], x1 = x[j1];
        v2f t, u;
        asm("v_pk_mul_f32 %0, %1, %2 op_sel:[1,1] op_sel_hi:[1,0] neg_hi:[1,0]"
            : "=v"(t) : "v"(P2), "v"(x1));
        asm("v_pk_fma_f32 %0, %1, %2, %0 op_sel:[1,0,0] op_sel_hi:[1,1,1] neg_lo:[1,0,0] neg_hi:[1,0,0]"
            : "+v"(t) : "v"(P1), "v"(x1));
        asm("v_pk_fma_f32 %0, %1, %2, %0 op_sel:[0,1,0] op_sel_hi:[0,0,1] neg_lo:[1,0,0]"
            : "+v"(t) : "v"(P2), "v"(x0));
        asm("v_pk_fma_f32 %0, %1, %2, %0 op_sel:[0,0,0] op_sel_hi:[0,1,1]"
            : "+v"(t) : "v"(P1), "v"(x0));
        asm("v_pk_mul_f32 %0, %1, %2 op_sel:[0,1] op_sel_hi:[0,0] neg_hi:[1,0]"
            : "=v"(u) : "v"(P2), "v"(x1));
        asm("v_pk_fma_f32 %0, %1, %2, %0 op_sel:[0,0,0] op_sel_hi:[0,1,1]"
            : "+v"(u) : "v"(P1), "v"(x1));
        asm("v_pk_fma_f32 %0, %1, %2, %0 op_sel:[1,1,0] op_sel_hi:[1,0,1] neg_hi:[1,0,0]"
            : "+v"(u) : "v"(P2), "v"(x0));
        asm("v_pk_fma_f32 %0, %1, %2, %0 op_sel:[1,0,0] op_sel_hi:[1,1,1]"
            : "+v"(u) : "v"(P1), "v"(x0));
        x[j0] = t; x[j1] = u;
    }
}

// CZ diagonal: sign = czP5(j) ^ base(j), base selected per compile-time j among
// 4 runtime sign words. XL: X layout (cross term on j bit5), else Y (j bit0).
template<bool XL>
__device__ __forceinline__ void applyCZ(v2f (&x)[64], unsigned w0, unsigned w0s,
                                        unsigned w1, unsigned w1s) {
#pragma unroll
    for (int j = 0; j < 64; ++j) {
        const bool hi = XL ? ((j & 32) != 0) : ((j & 1) != 0);
        const unsigned wo = czP5(j) ? (hi ? w1s : w0s) : (hi ? w1 : w0);
        x[j].x = __uint_as_float(__float_as_uint(x[j].x) ^ wo);
        x[j].y = __uint_as_float(__float_as_uint(x[j].y) ^ wo);
    }
}

#define WAVEWAIT() asm volatile("s_waitcnt lgkmcnt(0)" ::: "memory")

// 6+6 partition: X layout = lane holds amps (lane<<6)|j (j = amp bits 0-5),
// Y layout = lane holds amps (j<<6)|lane. One wave per batch item; all layout
// exchanges are intra-wave 64x64 transposes through a wave-private, XOR-swizzled
// LDS buffer (phys col = col ^ (row&30)) -> zero __syncthreads in the kernel.
// Half-pass schedule (8 x 6 gates): X0|Y0+CZ0|Y1|X1+CZ1|X2|Y2+CZ2|Y3|X3+CZ3.
__global__ __launch_bounds__(128, 1) void qddpm_kernel(
    const float* __restrict__ in_re,
    const float* __restrict__ in_im,
    const float* __restrict__ params,
    const float* __restrict__ uu,
    float* __restrict__ out)
{
    __shared__ v2f S[WPB * DIM];          // 2 x 32 KB = 64 KB, wave-private slices

    const int tid  = threadIdx.x;
    const int w    = tid >> 6;
    const int lane = tid & 63;
    const int b    = blockIdx.x * WPB + w;
    v2f* Sw = S + w * DIM;

    const float uval = uu[b];

    // ---- global -> registers, X layout (contiguous 512 B per lane) ----
    v2f x[64];
    {
        const float4* re4 = (const float4*)(in_re + (size_t)b * DIM + lane * 64);
        const float4* im4 = (const float4*)(in_im + (size_t)b * DIM + lane * 64);
#pragma unroll
        for (int q = 0; q < 16; ++q) {
            const float4 vr = re4[q];
            const float4 vi = im4[q];
            x[4 * q + 0] = (v2f){vr.x, vi.x};
            x[4 * q + 1] = (v2f){vr.y, vi.y};
            x[4 * q + 2] = (v2f){vr.z, vi.z};
            x[4 * q + 3] = (v2f){vr.w, vi.w};
        }
    }

    // ---- per-wave gate coefficients in registers: lane g (g<48) holds gate g's
    // (cc,cs,ss,sc); fetched later via readlane (wave-uniform index). ----
    float gv0 = 0.f, gv1 = 0.f, gv2 = 0.f, gv3 = 0.f;
    if (lane < 48) {
        const int lay = lane / 12, q = lane - lay * 12;
        float c1, s1, c2, s2;
        sincosf(params[lay * 24 + q] * 0.5f, &s1, &c1);
        sincosf(params[lay * 24 + 12 + q] * 0.5f, &s2, &c2);
        gv0 = c1 * c2; gv1 = c1 * s2; gv2 = s1 * s2; gv3 = s1 * c2;
    }

    // ---- CZ sign words (bit31 xor masks) ----
    const unsigned SGN = 0x80000000u;
    const unsigned ct  = (unsigned)czP5(lane) << 31;           // pairs within lane's 6 bits
    const unsigned sx1 = ct ^ ((unsigned)(lane & 1) << 31);         // X cross: j5 & lane0
    const unsigned sy1 = ct ^ ((unsigned)((lane >> 5) & 1) << 31);  // Y cross: lane5 & j0

#pragma clang loop unroll(disable)
    for (int h = 0; h < 8; ++h) {
        const int  l   = h >> 1;
        const int  hm4 = h & 3;
        const bool isX = (hm4 == 0) || (hm4 == 3);
        const int  cb  = l * 12 + (isX ? 6 : 0);   // gate idx = cb + 5 - G

        // ---- 6 gates on local bits (coeffs broadcast from lane cb+5-G) ----
        v2f P1, P2;
#define GETP(GL) \
        P1.x = __int_as_float(__builtin_amdgcn_readlane(__float_as_int(gv0), (GL))); \
        P1.y = __int_as_float(__builtin_amdgcn_readlane(__float_as_int(gv1), (GL))); \
        P2.x = __int_as_float(__builtin_amdgcn_readlane(__float_as_int(gv2), (GL))); \
        P2.y = __int_as_float(__builtin_amdgcn_readlane(__float_as_int(gv3), (GL)))
        GETP(cb + 5); gate_pk<0>(x, P1, P2);
        GETP(cb + 4); gate_pk<1>(x, P1, P2);
        GETP(cb + 3); gate_pk<2>(x, P1, P2);
        GETP(cb + 2); gate_pk<3>(x, P1, P2);
        GETP(cb + 1); gate_pk<4>(x, P1, P2);
        GETP(cb + 0); gate_pk<5>(x, P1, P2);
#undef GETP

        if (h & 1) {
            // CZ for layer l, in the current layout
            if ((h >> 1) & 1) applyCZ<true >(x, ct, ct ^ SGN, sx1, sx1 ^ SGN);
            else              applyCZ<false>(x, ct, ct ^ SGN, sy1, sy1 ^ SGN);
        } else {
            // intra-wave 64x64 transpose, XOR-swizzled: phys col = c ^ (row & 30)
            WAVEWAIT();                              // WAR vs previous reads
            if (((h >> 1) & 1) == 0) {
                // X -> Y: write rows (b128 pairs), read columns (b64)
                {
                    float4* wb = (float4*)((char*)Sw + lane * 512);
                    const unsigned hs = (unsigned)(lane & 30) >> 1;
#pragma unroll
                    for (int c = 0; c < 64; c += 2)
                        wb[(unsigned)(c >> 1) ^ hs] =
                            make_float4(x[c].x, x[c].y, x[c + 1].x, x[c + 1].y);
                }
                WAVEWAIT();
#pragma unroll
                for (int r = 0; r < 64; ++r) {
                    const v2f* rb = (const v2f*)((char*)Sw +
                        (((unsigned)(lane ^ (r & 30))) << 3));
                    x[r] = rb[r * 64];
                }
            } else {
                // Y -> X: write columns (b64), read rows (b128 pairs)
#pragma unroll
                for (int r = 0; r < 64; ++r) {
                    v2f* wb = (v2f*)((char*)Sw +
                        (((unsigned)(lane ^ (r & 30))) << 3));
                    wb[r * 64] = x[r];
                }
                WAVEWAIT();
                {
                    const float4* rb = (const float4*)((char*)Sw + lane * 512);
                    const unsigned hs = (unsigned)(lane & 30) >> 1;
#pragma unroll
                    for (int c = 0; c < 64; c += 2) {
                        const float4 v = rb[(unsigned)(c >> 1) ^ hs];
                        x[c]     = (v2f){v.x, v.y};
                        x[c + 1] = (v2f){v.z, v.w};
                    }
                }
            }
        }
    }

    // ---- probs: final X layout, lane holds amps (lane<<6)|j ; outcome = lane>>2 ----
    v2f acc = (v2f){0.f, 0.f};
#pragma unroll
    for (int j = 0; j < 64; ++j) acc += x[j] * x[j];
    float partial = acc.x + acc.y;
    partial += __shfl_xor(partial, 1);
    partial += __shfl_xor(partial, 2);          // 4-lane outcome groups summed

    float pr[16];
#pragma unroll
    for (int g = 0; g < 16; ++g) pr[g] = __shfl(partial, g * 4);

    // ---- redundant per-lane inverse-CDF sample + output [B, 256, 2] ----
    float cdf[16];
    float a = 0.f;
#pragma unroll
    for (int g = 0; g < 16; ++g) { a += pr[g]; cdf[g] = a; }
    const float thresh = uval * a;
    int m = 0;
#pragma unroll
    for (int g = 15; g >= 0; --g) { if (cdf[g] >= thresh) m = g; }
    float pm = pr[0];
#pragma unroll
    for (int g = 1; g < 16; ++g) { if (m == g) pm = pr[g]; }
    const float rn = 1.0f / sqrtf(pm);

    if ((lane >> 2) == m) {                      // 4 lanes own the collapsed state
        float4* o = (float4*)((float2*)out + (size_t)b * 256 + (lane & 3) * 64);
#pragma unroll
        for (int q = 0; q < 32; ++q)
            o[q] = make_float4(x[2 * q].x * rn, x[2 * q].y * rn,
                               x[2 * q + 1].x * rn, x[2 * q + 1].y * rn);
    }
}

extern "C" void kernel_launch(void* const* d_in, const int* in_sizes, int n_in,
                              void* d_out, int out_size, void* d_ws, size_t ws_size,
                              hipStream_t stream) {
    const float* in_re  = (const float*)d_in[0];
    const float* in_im  = (const float*)d_in[1];
    const float* params = (const float*)d_in[2];
    const float* u      = (const float*)d_in[3];
    float* out = (float*)d_out;
    qddpm_kernel<<<NBLK, 128, 0, stream>>>(in_re, in_im, params, u, out);
}